// Round 1
// baseline (20125.664 us; speedup 1.0000x reference)
//
#include <hip/hip_runtime.h>
#include <math.h>

#define BB 64
#define TT 4096
#define WW 64
#define MODES 32
#define NLAYER 4
#define OUTT 4096
#define KSPLIT 8

// ws layout (float offsets)
#define OFF_H     0                      // [B][W][T]  16,777,216
#define OFF_FTAB  16777216               // [T][64]       262,144
#define OFF_ITAB  17039360               // [64][T]       262,144
#define OFF_XF    17301504               // [B*W][64]     262,144
#define OFF_Y     17563648               // [B*W][64]     262,144
#define OFF_S     17825792               // [B][T]        262,144
#define OFF_PART  18087936               // [8][4096][64] 2,097,152 (shared dft/tok partials)

__device__ __forceinline__ float gelu_exact(float x) {
    return 0.5f * x * (1.0f + erff(x * 0.70710678118654752f));
}

// ---------------- tables ----------------
__global__ __launch_bounds__(256) void build_tables_kernel(float* __restrict__ ftab,
                                                           float* __restrict__ itab) {
    const int idx = blockIdx.x * 256 + threadIdx.x;   // 0 .. 64*T-1
    const float w0 = 6.28318530717958647692f / (float)TT;
    // ftab [t][j]: j<32 -> cos(2pi m t/T); j>=32 -> -sin(...)
    {
        int t = idx >> 6, j = idx & 63, m = j & 31;
        float ang = (float)((m * t) & (TT - 1)) * w0;
        float s, c; sincosf(ang, &s, &c);
        ftab[idx] = (j < 32) ? c : -s;
    }
    // itab [j][t]: j=0 -> 1/T ; 1<=j<32 -> 2/T cos ; j=32 -> 0 ; j>32 -> -2/T sin
    {
        int j = idx >> 12, t = idx & (TT - 1), m = j & 31;
        float ang = (float)((m * t) & (TT - 1)) * w0;
        float s, c; sincosf(ang, &s, &c);
        float v;
        if (j == 0)       v = 1.0f / (float)TT;
        else if (j < 32)  v = (2.0f / (float)TT) * c;
        else if (j == 32) v = 0.0f;
        else              v = -(2.0f / (float)TT) * s;
        itab[idx] = v;
    }
}

// ---------------- lift ----------------
__global__ __launch_bounds__(256) void lift_kernel(const float* __restrict__ x,
                                                   const float* __restrict__ lw,
                                                   const float* __restrict__ lb,
                                                   float* __restrict__ h) {
    int idx = blockIdx.x * 256 + threadIdx.x;      // over B*W*T
    int t = idx & (TT - 1);
    int w = (idx >> 12) & 63;
    int b = idx >> 18;
    h[idx] = x[b * TT + t] * lw[w] + lb[w];
}

// ---------------- DFT partial: Cp[kc][row][j] = sum_{k in chunk} h[row][k]*ftab[k][j] ----
__global__ __launch_bounds__(256) void dft_partial_kernel(const float* __restrict__ A,
                                                          const float* __restrict__ Btab,
                                                          float* __restrict__ Cp) {
    __shared__ float As[64][65];
    __shared__ float Bs[64][65];
    const int row0 = blockIdx.x << 6;
    const int kc   = blockIdx.y;
    const int tid  = threadIdx.x;
    const int tx = tid & 15, ty = tid >> 4;
    float acc[4][4] = {};
    int k0 = kc * (TT / KSPLIT);
    for (int kt = 0; kt < (TT / KSPLIT) / 64; ++kt, k0 += 64) {
        #pragma unroll
        for (int i = 0; i < 16; ++i) {
            int idx = tid + (i << 8);
            int r = idx >> 6, c = idx & 63;
            As[r][c] = A[(row0 + r) * TT + k0 + c];
            Bs[r][c] = Btab[(k0 + r) * 64 + c];
        }
        __syncthreads();
        #pragma unroll
        for (int k = 0; k < 64; ++k) {
            float av[4], bv[4];
            #pragma unroll
            for (int i = 0; i < 4; ++i) av[i] = As[ty * 4 + i][k];
            #pragma unroll
            for (int j = 0; j < 4; ++j) bv[j] = Bs[k][tx * 4 + j];
            #pragma unroll
            for (int i = 0; i < 4; ++i)
                #pragma unroll
                for (int j = 0; j < 4; ++j) acc[i][j] += av[i] * bv[j];
        }
        __syncthreads();
    }
    #pragma unroll
    for (int i = 0; i < 4; ++i)
        #pragma unroll
        for (int j = 0; j < 4; ++j)
            Cp[(kc << 18) + (row0 + ty * 4 + i) * 64 + tx * 4 + j] = acc[i][j];
}

__global__ __launch_bounds__(256) void reduce8_kernel(const float* __restrict__ Cp,
                                                      float* __restrict__ C) {
    int idx = blockIdx.x * 256 + threadIdx.x;   // 262144
    float v = 0.f;
    #pragma unroll
    for (int kc = 0; kc < KSPLIT; ++kc) v += Cp[(kc << 18) + idx];
    C[idx] = v;
}

// ---------------- spectral mix ----------------
__global__ __launch_bounds__(256) void specmix_kernel(const float* __restrict__ XF,
                                                      const float* __restrict__ wr,
                                                      const float* __restrict__ wi,
                                                      float* __restrict__ Y) {
    int tid = blockIdx.x * 256 + threadIdx.x;   // 131072
    int m = tid & 31, o = (tid >> 5) & 63, b = tid >> 11;
    float yr = 0.f, yi = 0.f;
    #pragma unroll 4
    for (int i = 0; i < WW; ++i) {
        float xr = XF[((b << 6) + i) * 64 + m];
        float xi = XF[((b << 6) + i) * 64 + 32 + m];
        float ar = wr[((i << 6) + o) * 32 + m];
        float ai = wi[((i << 6) + o) * 32 + m];
        yr += xr * ar - xi * ai;
        yi += xr * ai + xi * ar;
    }
    Y[((b << 6) + o) * 64 + m]      = yr;
    Y[((b << 6) + o) * 64 + 32 + m] = yi;
}

// ------------- fused iDFT + pointwise conv + bias + GELU, in-place on h -------------
__global__ __launch_bounds__(256) void idft_pw_kernel(const float* __restrict__ Y,
                                                      const float* __restrict__ itab,
                                                      const float* __restrict__ pww,
                                                      const float* __restrict__ pwb,
                                                      float* __restrict__ h) {
    __shared__ float Ta[64][65];
    __shared__ float Tb[64][65];
    const int b  = blockIdx.y;
    const int t0 = blockIdx.x << 6;
    const int tid = threadIdx.x;
    const int tx = tid & 15, ty = tid >> 4;
    float acc[4][4] = {};

    // phase 1: spec = Y[b] (64x64) x itab[:, t-tile] (64x64)
    #pragma unroll
    for (int i = 0; i < 16; ++i) {
        int idx = tid + (i << 8);
        int r = idx >> 6, c = idx & 63;
        Ta[r][c] = Y[((b << 6) + r) * 64 + c];
        Tb[r][c] = itab[(r << 12) + t0 + c];
    }
    __syncthreads();
    #pragma unroll
    for (int k = 0; k < 64; ++k) {
        float av[4], bv[4];
        #pragma unroll
        for (int i = 0; i < 4; ++i) av[i] = Ta[ty * 4 + i][k];
        #pragma unroll
        for (int j = 0; j < 4; ++j) bv[j] = Tb[k][tx * 4 + j];
        #pragma unroll
        for (int i = 0; i < 4; ++i)
            #pragma unroll
            for (int j = 0; j < 4; ++j) acc[i][j] += av[i] * bv[j];
    }
    __syncthreads();

    // phase 2: pw = pw_w (64x64) x h[b][:, t-tile] (64x64)
    #pragma unroll
    for (int i = 0; i < 16; ++i) {
        int idx = tid + (i << 8);
        int r = idx >> 6, c = idx & 63;
        Ta[r][c] = pww[(r << 6) + c];
        Tb[r][c] = h[((b << 6) + r) * TT + t0 + c];
    }
    __syncthreads();
    #pragma unroll
    for (int k = 0; k < 64; ++k) {
        float av[4], bv[4];
        #pragma unroll
        for (int i = 0; i < 4; ++i) av[i] = Ta[ty * 4 + i][k];
        #pragma unroll
        for (int j = 0; j < 4; ++j) bv[j] = Tb[k][tx * 4 + j];
        #pragma unroll
        for (int i = 0; i < 4; ++i)
            #pragma unroll
            for (int j = 0; j < 4; ++j) acc[i][j] += av[i] * bv[j];
    }

    // epilogue: + pw_b, gelu, write back in place
    #pragma unroll
    for (int i = 0; i < 4; ++i) {
        int o = ty * 4 + i;
        float bias = pwb[o];
        #pragma unroll
        for (int j = 0; j < 4; ++j) {
            float v = acc[i][j] + bias;
            h[((b << 6) + o) * TT + t0 + tx * 4 + j] = gelu_exact(v);
        }
    }
}

// ------------- fused proj1(gelu) + proj2 -> s[B][T] -------------
__global__ __launch_bounds__(256) void proj_kernel(const float* __restrict__ h,
                                                   const float* __restrict__ p1w,
                                                   const float* __restrict__ p1b,
                                                   const float* __restrict__ p2w,
                                                   const float* __restrict__ p2b,
                                                   float* __restrict__ s) {
    __shared__ float Hs[64][65];   // [w][t]
    __shared__ float Ws[64][65];   // [w'][w]
    __shared__ float red[4][64];
    const int b  = blockIdx.y;
    const int t0 = blockIdx.x << 6;
    const int tid = threadIdx.x;
    #pragma unroll
    for (int i = 0; i < 16; ++i) {
        int idx = tid + (i << 8);
        int r = idx >> 6, c = idx & 63;
        Hs[r][c] = h[((b << 6) + r) * TT + t0 + c];
        Ws[r][c] = p1w[(r << 6) + c];
    }
    __syncthreads();
    const int t = tid & 63, q = tid >> 6;
    float part = 0.f;
    for (int wp = q * 16; wp < q * 16 + 16; ++wp) {
        float a = p1b[wp];
        #pragma unroll 8
        for (int w = 0; w < 64; ++w) a += Ws[wp][w] * Hs[w][t];
        part += gelu_exact(a) * p2w[wp];
    }
    red[q][t] = part;
    __syncthreads();
    if (q == 0)
        s[b * TT + t0 + t] = red[0][t] + red[1][t] + red[2][t] + red[3][t] + p2b[0];
}

// ------------- token mixing: out[b][u] = tok_b[u] + sum_t s[b][t] tok_w[u][t] -------------
__global__ __launch_bounds__(256) void tok_partial_kernel(const float* __restrict__ S,
                                                          const float* __restrict__ tokw,
                                                          float* __restrict__ Cp) {
    __shared__ float As[64][65];   // [b][k]
    __shared__ float Bs[64][65];   // [k][u]
    const int u0 = blockIdx.x << 6;
    const int kc = blockIdx.y;
    const int tid = threadIdx.x;
    const int tx = tid & 15, ty = tid >> 4;
    float acc[4][4] = {};
    int k0 = kc * (TT / KSPLIT);
    for (int kt = 0; kt < (TT / KSPLIT) / 64; ++kt, k0 += 64) {
        #pragma unroll
        for (int i = 0; i < 16; ++i) {
            int idx = tid + (i << 8);
            int r = idx >> 6, c = idx & 63;
            As[r][c] = S[r * TT + k0 + c];
            int u = idx >> 6, kk = idx & 63;
            Bs[kk][u] = tokw[(u0 + u) * TT + k0 + kk];
        }
        __syncthreads();
        #pragma unroll
        for (int k = 0; k < 64; ++k) {
            float av[4], bv[4];
            #pragma unroll
            for (int i = 0; i < 4; ++i) av[i] = As[ty * 4 + i][k];
            #pragma unroll
            for (int j = 0; j < 4; ++j) bv[j] = Bs[k][tx * 4 + j];
            #pragma unroll
            for (int i = 0; i < 4; ++i)
                #pragma unroll
                for (int j = 0; j < 4; ++j) acc[i][j] += av[i] * bv[j];
        }
        __syncthreads();
    }
    // Cp layout: [kc][b(64)][u(4096)]
    #pragma unroll
    for (int i = 0; i < 4; ++i)
        #pragma unroll
        for (int j = 0; j < 4; ++j)
            Cp[(kc << 18) + (ty * 4 + i) * OUTT + u0 + tx * 4 + j] = acc[i][j];
}

__global__ __launch_bounds__(256) void tok_reduce_kernel(const float* __restrict__ Cp,
                                                         const float* __restrict__ tokb,
                                                         float* __restrict__ out) {
    int idx = blockIdx.x * 256 + threadIdx.x;   // 262144
    int u = idx & (OUTT - 1);
    float v = tokb[u];
    #pragma unroll
    for (int kc = 0; kc < KSPLIT; ++kc) v += Cp[(kc << 18) + idx];
    out[idx] = v;
}

extern "C" void kernel_launch(void* const* d_in, const int* in_sizes, int n_in,
                              void* d_out, int out_size, void* d_ws, size_t ws_size,
                              hipStream_t stream) {
    const float* x    = (const float*)d_in[0];
    const float* lw   = (const float*)d_in[1];
    const float* lb   = (const float*)d_in[2];
    const float* swr  = (const float*)d_in[3];
    const float* swi  = (const float*)d_in[4];
    const float* pww  = (const float*)d_in[5];
    const float* pwb  = (const float*)d_in[6];
    const float* p1w  = (const float*)d_in[7];
    const float* p1b  = (const float*)d_in[8];
    const float* p2w  = (const float*)d_in[9];
    const float* p2b  = (const float*)d_in[10];
    const float* tokw = (const float*)d_in[11];
    const float* tokb = (const float*)d_in[12];
    float* out = (float*)d_out;

    float* ws   = (float*)d_ws;
    float* h    = ws + OFF_H;
    float* ftab = ws + OFF_FTAB;
    float* itab = ws + OFF_ITAB;
    float* xf   = ws + OFF_XF;
    float* y    = ws + OFF_Y;
    float* s    = ws + OFF_S;
    float* part = ws + OFF_PART;

    build_tables_kernel<<<(64 * TT) / 256, 256, 0, stream>>>(ftab, itab);
    lift_kernel<<<(BB * WW * TT) / 256, 256, 0, stream>>>(x, lw, lb, h);

    for (int l = 0; l < NLAYER; ++l) {
        dft_partial_kernel<<<dim3(64, KSPLIT), 256, 0, stream>>>(h, ftab, part);
        reduce8_kernel<<<(BB * WW * 64) / 256, 256, 0, stream>>>(part, xf);
        specmix_kernel<<<(BB * WW * MODES) / 256, 256, 0, stream>>>(
            xf, swr + (size_t)l * WW * WW * MODES, swi + (size_t)l * WW * WW * MODES, y);
        idft_pw_kernel<<<dim3(TT / 64, BB), 256, 0, stream>>>(
            y, itab, pww + (size_t)l * WW * WW, pwb + (size_t)l * WW, h);
    }

    proj_kernel<<<dim3(TT / 64, BB), 256, 0, stream>>>(h, p1w, p1b, p2w, p2b, s);
    tok_partial_kernel<<<dim3(OUTT / 64, KSPLIT), 256, 0, stream>>>(s, tokw, part);
    tok_reduce_kernel<<<(BB * OUTT) / 256, 256, 0, stream>>>(part, tokb, out);
}

// Round 2
// 605.729 us; speedup vs baseline: 33.2255x; 33.2255x over previous
//
#include <hip/hip_runtime.h>
#include <math.h>

#define BB 64
#define TT 4096
#define WW 64
#define MODES 32
#define NLAYER 4
#define OUTT 4096
#define KSPLIT 8
#define LDP 68   // padded LDS leading dim (68%8==4 -> float4 rows conflict-free)

// ws layout (float offsets)
#define OFF_H     0                      // [B][W][T]  16,777,216
#define OFF_FTAB  16777216               // [T][64]       262,144
#define OFF_ITAB  17039360               // [64][T]       262,144
#define OFF_XF    17301504               // [B*W][64]     262,144
#define OFF_Y     17563648               // [B*W][64]     262,144
#define OFF_S     17825792               // [B][T]        262,144
#define OFF_PART  18087936               // [8][4096][64] 2,097,152 (shared dft/tok partials)

__device__ __forceinline__ float gelu_exact(float x) {
    return 0.5f * x * (1.0f + erff(x * 0.70710678118654752f));
}

// 64x64x64 tile micro-kernel: acc[i][j] += sum_k At[k][ty*4+i] * Bs[k][tx*4+j]
// Both fragments are contiguous float4 LDS reads (conflict-free with LDP=68).
__device__ __forceinline__ void mm64(const float (*__restrict__ At)[LDP],
                                     const float (*__restrict__ Bs)[LDP],
                                     int tx, int ty, float acc[4][4]) {
    #pragma unroll 4
    for (int k = 0; k < 64; ++k) {
        float4 a4 = *(const float4*)&At[k][ty * 4];
        float4 b4 = *(const float4*)&Bs[k][tx * 4];
        float av[4] = {a4.x, a4.y, a4.z, a4.w};
        float bv[4] = {b4.x, b4.y, b4.z, b4.w};
        #pragma unroll
        for (int i = 0; i < 4; ++i)
            #pragma unroll
            for (int j = 0; j < 4; ++j)
                acc[i][j] = fmaf(av[i], bv[j], acc[i][j]);
    }
}

// ---------------- tables ----------------
__global__ __launch_bounds__(256) void build_tables_kernel(float* __restrict__ ftab,
                                                           float* __restrict__ itab) {
    const int idx = blockIdx.x * 256 + threadIdx.x;   // 0 .. 64*T-1
    const float w0 = 6.28318530717958647692f / (float)TT;
    // ftab [t][j]: j<32 -> cos(2pi m t/T); j>=32 -> -sin(...)
    {
        int t = idx >> 6, j = idx & 63, m = j & 31;
        float ang = (float)((m * t) & (TT - 1)) * w0;
        float s, c; sincosf(ang, &s, &c);
        ftab[idx] = (j < 32) ? c : -s;
    }
    // itab [j][t]: j=0 -> 1/T ; 1<=j<32 -> 2/T cos ; j=32 -> 0 ; j>32 -> -2/T sin
    {
        int j = idx >> 12, t = idx & (TT - 1), m = j & 31;
        float ang = (float)((m * t) & (TT - 1)) * w0;
        float s, c; sincosf(ang, &s, &c);
        float v;
        if (j == 0)       v = 1.0f / (float)TT;
        else if (j < 32)  v = (2.0f / (float)TT) * c;
        else if (j == 32) v = 0.0f;
        else              v = -(2.0f / (float)TT) * s;
        itab[idx] = v;
    }
}

// ---------------- lift ----------------
__global__ __launch_bounds__(256) void lift_kernel(const float* __restrict__ x,
                                                   const float* __restrict__ lw,
                                                   const float* __restrict__ lb,
                                                   float* __restrict__ h) {
    int idx = blockIdx.x * 256 + threadIdx.x;      // over B*W*T
    int t = idx & (TT - 1);
    int w = (idx >> 12) & 63;
    int b = idx >> 18;
    h[idx] = x[b * TT + t] * lw[w] + lb[w];
}

// ---------------- DFT partial: Cp[kc][row][j] = sum_{k in chunk} h[row][k]*ftab[k][j] ----
__global__ __launch_bounds__(256, 4) void dft_partial_kernel(const float* __restrict__ A,
                                                             const float* __restrict__ Btab,
                                                             float* __restrict__ Cp) {
    __shared__ float At[64][LDP];   // At[k][row]
    __shared__ float Bs[64][LDP];   // Bs[k][j]
    const int row0 = blockIdx.x << 6;
    const int kc   = blockIdx.y;
    const int tid  = threadIdx.x;
    const int tx = tid & 15, ty = tid >> 4;
    float acc[4][4] = {};
    int k0 = kc * (TT / KSPLIT);
    for (int kt = 0; kt < (TT / KSPLIT) / 64; ++kt, k0 += 64) {
        #pragma unroll
        for (int i = 0; i < 16; ++i) {
            int idx = tid + (i << 8);
            int r = idx >> 6, c = idx & 63;
            At[c][r] = A[(row0 + r) * TT + k0 + c];      // transposed store (amortized conflicts)
            Bs[r][c] = Btab[(k0 + r) * 64 + c];
        }
        __syncthreads();
        mm64(At, Bs, tx, ty, acc);
        __syncthreads();
    }
    #pragma unroll
    for (int i = 0; i < 4; ++i) {
        float4 v = {acc[i][0], acc[i][1], acc[i][2], acc[i][3]};
        *(float4*)&Cp[(kc << 18) + (row0 + ty * 4 + i) * 64 + tx * 4] = v;
    }
}

__global__ __launch_bounds__(256) void reduce8_kernel(const float* __restrict__ Cp,
                                                      float* __restrict__ C) {
    int idx = blockIdx.x * 256 + threadIdx.x;   // 262144
    float v = 0.f;
    #pragma unroll
    for (int kc = 0; kc < KSPLIT; ++kc) v += Cp[(kc << 18) + idx];
    C[idx] = v;
}

// ---------------- spectral mix ----------------
__global__ __launch_bounds__(256) void specmix_kernel(const float* __restrict__ XF,
                                                      const float* __restrict__ wr,
                                                      const float* __restrict__ wi,
                                                      float* __restrict__ Y) {
    int tid = blockIdx.x * 256 + threadIdx.x;   // 131072
    int m = tid & 31, o = (tid >> 5) & 63, b = tid >> 11;
    float yr = 0.f, yi = 0.f;
    #pragma unroll 4
    for (int i = 0; i < WW; ++i) {
        float xr = XF[((b << 6) + i) * 64 + m];
        float xi = XF[((b << 6) + i) * 64 + 32 + m];
        float ar = wr[((i << 6) + o) * 32 + m];
        float ai = wi[((i << 6) + o) * 32 + m];
        yr += xr * ar - xi * ai;
        yi += xr * ai + xi * ar;
    }
    Y[((b << 6) + o) * 64 + m]      = yr;
    Y[((b << 6) + o) * 64 + 32 + m] = yi;
}

// ------------- fused iDFT + pointwise conv + bias + GELU, in-place on h -------------
__global__ __launch_bounds__(256, 4) void idft_pw_kernel(const float* __restrict__ Y,
                                                         const float* __restrict__ itab,
                                                         const float* __restrict__ pww,
                                                         const float* __restrict__ pwb,
                                                         float* __restrict__ h) {
    __shared__ float At[64][LDP];
    __shared__ float Bs[64][LDP];
    const int b  = blockIdx.y;
    const int t0 = blockIdx.x << 6;
    const int tid = threadIdx.x;
    const int tx = tid & 15, ty = tid >> 4;
    float acc[4][4] = {};

    // phase 1: spec = Y[b] (64x64, A[o][j]) x itab[j][t-tile]
    #pragma unroll
    for (int i = 0; i < 16; ++i) {
        int idx = tid + (i << 8);
        int r = idx >> 6, c = idx & 63;
        At[c][r] = Y[((b << 6) + r) * 64 + c];
        Bs[r][c] = itab[(r << 12) + t0 + c];
    }
    __syncthreads();
    mm64(At, Bs, tx, ty, acc);
    __syncthreads();

    // phase 2: pw = pw_w (A[o][w]) x h[b][w][t-tile]
    #pragma unroll
    for (int i = 0; i < 16; ++i) {
        int idx = tid + (i << 8);
        int r = idx >> 6, c = idx & 63;
        At[c][r] = pww[(r << 6) + c];
        Bs[r][c] = h[((b << 6) + r) * TT + t0 + c];
    }
    __syncthreads();
    mm64(At, Bs, tx, ty, acc);

    // epilogue: + pw_b, gelu, write back in place (float4)
    #pragma unroll
    for (int i = 0; i < 4; ++i) {
        int o = ty * 4 + i;
        float bias = pwb[o];
        float4 v;
        v.x = gelu_exact(acc[i][0] + bias);
        v.y = gelu_exact(acc[i][1] + bias);
        v.z = gelu_exact(acc[i][2] + bias);
        v.w = gelu_exact(acc[i][3] + bias);
        *(float4*)&h[((b << 6) + o) * TT + t0 + tx * 4] = v;
    }
}

// ------------- fused proj1(gelu) + proj2 -> s[B][T] -------------
__global__ __launch_bounds__(256, 4) void proj_kernel(const float* __restrict__ h,
                                                      const float* __restrict__ p1w,
                                                      const float* __restrict__ p1b,
                                                      const float* __restrict__ p2w,
                                                      const float* __restrict__ p2b,
                                                      float* __restrict__ s) {
    __shared__ float Hs[64][LDP];   // [w][t]
    __shared__ float Ws[64][LDP];   // [w'][w]
    __shared__ float red[16][64];
    const int b  = blockIdx.y;
    const int t0 = blockIdx.x << 6;
    const int tid = threadIdx.x;
    const int tx = tid & 15, q = tid >> 4;   // tx: t-quad, q: w'-quad
    #pragma unroll
    for (int i = 0; i < 16; ++i) {
        int idx = tid + (i << 8);
        int r = idx >> 6, c = idx & 63;
        Hs[r][c] = h[((b << 6) + r) * TT + t0 + c];
        Ws[r][c] = p1w[(r << 6) + c];
    }
    __syncthreads();
    float4 part = {0.f, 0.f, 0.f, 0.f};
    #pragma unroll
    for (int wi = 0; wi < 4; ++wi) {
        int wp = (q << 2) + wi;
        float bias = p1b[wp];
        float4 a = {bias, bias, bias, bias};
        #pragma unroll 4
        for (int w = 0; w < 64; ++w) {
            float wsv = Ws[wp][w];
            float4 hv = *(const float4*)&Hs[w][tx * 4];
            a.x = fmaf(wsv, hv.x, a.x);
            a.y = fmaf(wsv, hv.y, a.y);
            a.z = fmaf(wsv, hv.z, a.z);
            a.w = fmaf(wsv, hv.w, a.w);
        }
        float pw2 = p2w[wp];
        part.x += gelu_exact(a.x) * pw2;
        part.y += gelu_exact(a.y) * pw2;
        part.z += gelu_exact(a.z) * pw2;
        part.w += gelu_exact(a.w) * pw2;
    }
    *(float4*)&red[q][tx * 4] = part;
    __syncthreads();
    if (tid < 64) {
        float v = p2b[0];
        #pragma unroll
        for (int qq = 0; qq < 16; ++qq) v += red[qq][tid];
        s[b * TT + t0 + tid] = v;
    }
}

// ------------- token mixing partials: out[b][u] = sum_t s[b][t] tok_w[u][t] -------------
__global__ __launch_bounds__(256, 4) void tok_partial_kernel(const float* __restrict__ S,
                                                             const float* __restrict__ tokw,
                                                             float* __restrict__ Cp) {
    __shared__ float At[64][LDP];   // At[k][b-row]
    __shared__ float Bs[64][LDP];   // Bs[k][u]
    const int u0 = blockIdx.x << 6;
    const int kc = blockIdx.y;
    const int tid = threadIdx.x;
    const int tx = tid & 15, ty = tid >> 4;
    float acc[4][4] = {};
    int k0 = kc * (TT / KSPLIT);
    for (int kt = 0; kt < (TT / KSPLIT) / 64; ++kt, k0 += 64) {
        #pragma unroll
        for (int i = 0; i < 16; ++i) {
            int idx = tid + (i << 8);
            int r = idx >> 6, c = idx & 63;
            At[c][r] = S[r * TT + k0 + c];                 // A[brow][k] transposed
            Bs[c][r] = tokw[(u0 + r) * TT + k0 + c];       // B[k][u] = tokw[u][k] transposed
        }
        __syncthreads();
        mm64(At, Bs, tx, ty, acc);
        __syncthreads();
    }
    // Cp layout: [kc][b(64)][u(4096)]
    #pragma unroll
    for (int i = 0; i < 4; ++i) {
        float4 v = {acc[i][0], acc[i][1], acc[i][2], acc[i][3]};
        *(float4*)&Cp[(kc << 18) + (ty * 4 + i) * OUTT + u0 + tx * 4] = v;
    }
}

__global__ __launch_bounds__(256) void tok_reduce_kernel(const float* __restrict__ Cp,
                                                         const float* __restrict__ tokb,
                                                         float* __restrict__ out) {
    int idx = blockIdx.x * 256 + threadIdx.x;   // 262144
    int u = idx & (OUTT - 1);
    float v = tokb[u];
    #pragma unroll
    for (int kc = 0; kc < KSPLIT; ++kc) v += Cp[(kc << 18) + idx];
    out[idx] = v;
}

extern "C" void kernel_launch(void* const* d_in, const int* in_sizes, int n_in,
                              void* d_out, int out_size, void* d_ws, size_t ws_size,
                              hipStream_t stream) {
    const float* x    = (const float*)d_in[0];
    const float* lw   = (const float*)d_in[1];
    const float* lb   = (const float*)d_in[2];
    const float* swr  = (const float*)d_in[3];
    const float* swi  = (const float*)d_in[4];
    const float* pww  = (const float*)d_in[5];
    const float* pwb  = (const float*)d_in[6];
    const float* p1w  = (const float*)d_in[7];
    const float* p1b  = (const float*)d_in[8];
    const float* p2w  = (const float*)d_in[9];
    const float* p2b  = (const float*)d_in[10];
    const float* tokw = (const float*)d_in[11];
    const float* tokb = (const float*)d_in[12];
    float* out = (float*)d_out;

    float* ws   = (float*)d_ws;
    float* h    = ws + OFF_H;
    float* ftab = ws + OFF_FTAB;
    float* itab = ws + OFF_ITAB;
    float* xf   = ws + OFF_XF;
    float* y    = ws + OFF_Y;
    float* s    = ws + OFF_S;
    float* part = ws + OFF_PART;

    build_tables_kernel<<<(64 * TT) / 256, 256, 0, stream>>>(ftab, itab);
    lift_kernel<<<(BB * WW * TT) / 256, 256, 0, stream>>>(x, lw, lb, h);

    for (int l = 0; l < NLAYER; ++l) {
        dft_partial_kernel<<<dim3(64, KSPLIT), 256, 0, stream>>>(h, ftab, part);
        reduce8_kernel<<<(BB * WW * 64) / 256, 256, 0, stream>>>(part, xf);
        specmix_kernel<<<(BB * WW * MODES) / 256, 256, 0, stream>>>(
            xf, swr + (size_t)l * WW * WW * MODES, swi + (size_t)l * WW * WW * MODES, y);
        idft_pw_kernel<<<dim3(TT / 64, BB), 256, 0, stream>>>(
            y, itab, pww + (size_t)l * WW * WW, pwb + (size_t)l * WW, h);
    }

    proj_kernel<<<dim3(TT / 64, BB), 256, 0, stream>>>(h, p1w, p1b, p2w, p2b, s);
    tok_partial_kernel<<<dim3(OUTT / 64, KSPLIT), 256, 0, stream>>>(s, tokw, part);
    tok_reduce_kernel<<<(BB * OUTT) / 256, 256, 0, stream>>>(part, tokb, out);
}

// Round 3
// 559.544 us; speedup vs baseline: 35.9679x; 1.0825x over previous
//
#include <hip/hip_runtime.h>
#include <math.h>
#include <stdint.h>

#define BB 64
#define TT 4096
#define WW 64
#define MODES 32
#define NLAYER 4
#define OUTT 4096
#define KSPLIT 8

typedef uint32_t u32;
typedef __attribute__((ext_vector_type(8))) short bf16x8;
typedef __attribute__((ext_vector_type(16))) float f32x16;

// ws layout (float offsets)
#define OFF_HC   0            // hc[b][t][w] packed bf16 hi|lo, 16,777,216 u32
#define OFF_FTH  16777216     // ftabT_hi [64 j][4096 t] ushort (131072 floats)
#define OFF_FTL  16908288
#define OFF_ITH  17039360     // itabT_hi [4096 t][64 j] ushort
#define OFF_ITL  17170432
#define OFF_PWH  17301504     // pww planes [4][64][64] ushort (8192 floats)
#define OFF_PWL  17309696
#define OFF_P1H  17317888     // p1w planes [64][64] ushort (2048 floats)
#define OFF_P1L  17319936
#define OFF_YH   17321984     // Y_hi [4096 (b,o)][64 j] ushort (131072 floats)
#define OFF_YL   17453056
#define OFF_XFP  17584128     // xfPart [8][64][64][64] f32 (2,097,152) -- shared with tokPart
#define OFF_XFB  19681280     // xfb [64][64][64] f32 (262,144)
#define OFF_SC   19943424     // sc [64][4096] packed u32 (262,144)

__device__ __forceinline__ float gelu_exact(float x) {
    return 0.5f * x * (1.0f + erff(x * 0.70710678118654752f));
}

__device__ __forceinline__ u32 bfrn(float f) {
    u32 u = __float_as_uint(f);
    return (u + 0x7fffu + ((u >> 16) & 1u)) >> 16;
}
// packed word: low16 = bf16(hi), high16 = bf16(residual)
__device__ __forceinline__ u32 packf(float f) {
    u32 h = bfrn(f);
    float r = f - __uint_as_float(h << 16);
    u32 l = bfrn(r);
    return h | (l << 16);
}
__device__ __forceinline__ void unpack8(const u32* w, bf16x8& hi, bf16x8& lo) {
    union { bf16x8 v; ushort u[8]; } H, L;
    #pragma unroll
    for (int i = 0; i < 8; ++i) { H.u[i] = (ushort)(w[i] & 0xffffu); L.u[i] = (ushort)(w[i] >> 16); }
    hi = H.v; lo = L.v;
}
__device__ __forceinline__ void cvt8(const float* f, bf16x8& hi, bf16x8& lo) {
    union { bf16x8 v; ushort u[8]; } H, L;
    #pragma unroll
    for (int i = 0; i < 8; ++i) {
        u32 h = bfrn(f[i]);
        H.u[i] = (ushort)h;
        L.u[i] = (ushort)bfrn(f[i] - __uint_as_float(h << 16));
    }
    hi = H.v; lo = L.v;
}

// 3-term split mfma: acc += (ah+al)*(bh+bl) to ~2^-18 relative
#define MM3(ah, al, bh, bl, acc)                                          \
    acc = __builtin_amdgcn_mfma_f32_32x32x16_bf16(ah, bh, acc, 0, 0, 0);  \
    acc = __builtin_amdgcn_mfma_f32_32x32x16_bf16(ah, bl, acc, 0, 0, 0);  \
    acc = __builtin_amdgcn_mfma_f32_32x32x16_bf16(al, bh, acc, 0, 0, 0);

#define ACC_ZERO(acc) { _Pragma("unroll") for (int _i = 0; _i < 16; ++_i) acc[_i] = 0.0f; }

// ---------------- tables (bf16 hi/lo planes, transposed layouts) ----------------
__global__ __launch_bounds__(256) void build_tables_kernel(ushort* __restrict__ fth, ushort* __restrict__ ftl,
                                                           ushort* __restrict__ ith, ushort* __restrict__ itl) {
    const int idx = blockIdx.x * 256 + threadIdx.x;   // 0..262143
    const float w0 = 6.28318530717958647692f / (float)TT;
    {   // ftabT [j][t]: j<32 -> cos(2pi m t/T); j>=32 -> -sin
        int j = idx >> 12, t = idx & (TT - 1), m = j & 31;
        float ang = (float)((m * t) & (TT - 1)) * w0;
        float s, c; sincosf(ang, &s, &c);
        u32 p = packf((j < 32) ? c : -s);
        fth[idx] = (ushort)(p & 0xffffu); ftl[idx] = (ushort)(p >> 16);
    }
    {   // itabT [t][j]: j=0 -> 1/T ; 1<=j<32 -> 2/T cos ; j=32 -> 0 ; j>32 -> -2/T sin
        int t = idx >> 6, j = idx & 63, m = j & 31;
        float ang = (float)((m * t) & (TT - 1)) * w0;
        float s, c; sincosf(ang, &s, &c);
        float v;
        if (j == 0)       v = 1.0f / (float)TT;
        else if (j < 32)  v = (2.0f / (float)TT) * c;
        else if (j == 32) v = 0.0f;
        else              v = -(2.0f / (float)TT) * s;
        u32 p = packf(v);
        ith[idx] = (ushort)(p & 0xffffu); itl[idx] = (ushort)(p >> 16);
    }
}

// ---------------- weight conversion ----------------
__global__ __launch_bounds__(256) void wconv_kernel(const float* __restrict__ pww, const float* __restrict__ p1w,
                                                    ushort* __restrict__ pwh, ushort* __restrict__ pwl,
                                                    ushort* __restrict__ p1h, ushort* __restrict__ p1l) {
    int idx = blockIdx.x * 256 + threadIdx.x;   // 0..20479
    if (idx < NLAYER * 64 * 64) {
        u32 p = packf(pww[idx]);
        pwh[idx] = (ushort)(p & 0xffffu); pwl[idx] = (ushort)(p >> 16);
    } else if (idx < NLAYER * 64 * 64 + 64 * 64) {
        int k = idx - NLAYER * 64 * 64;
        u32 p = packf(p1w[k]);
        p1h[k] = (ushort)(p & 0xffffu); p1l[k] = (ushort)(p >> 16);
    }
}

// ---------------- lift -> hc[b][t][w] ----------------
__global__ __launch_bounds__(256) void lift_kernel(const float* __restrict__ x,
                                                   const float* __restrict__ lw,
                                                   const float* __restrict__ lb,
                                                   u32* __restrict__ hc) {
    int idx = blockIdx.x * 256 + threadIdx.x;      // B*T*W
    int w = idx & 63;
    int bt = idx >> 6;
    hc[idx] = packf(x[bt] * lw[w] + lb[w]);
}

// ---------------- DFT: xfPart[kc][b][j][w] = sum_{t in chunk} ftabT[j][t] * h[b][t][w] ----
__global__ __launch_bounds__(256) void dft_kernel(const u32* __restrict__ hc,
                                                  const ushort* __restrict__ fth,
                                                  const ushort* __restrict__ ftl,
                                                  float* __restrict__ xfp) {
    const int b = blockIdx.x, kc = blockIdx.y;
    const int tid = threadIdx.x, l = tid & 63, q = tid >> 6;
    const int mt = q >> 1, nt = q & 1;
    const int lj = mt * 32 + (l & 31);      // j (A row)
    const int wv = nt * 32 + (l & 31);      // w (B col)
    const int kh = (l >> 5) * 8;
    f32x16 acc; ACC_ZERO(acc);
    for (int ks = 0; ks < 32; ++ks) {
        const int k0 = kc * 512 + ks * 16 + kh;     // t offset
        bf16x8 ah = *(const bf16x8*)(fth + (size_t)lj * TT + k0);
        bf16x8 al = *(const bf16x8*)(ftl + (size_t)lj * TT + k0);
        u32 wbuf[8];
        const u32* p = hc + ((size_t)b * TT + k0) * 64 + wv;
        #pragma unroll
        for (int i = 0; i < 8; ++i) wbuf[i] = p[(size_t)i * 64];
        bf16x8 bh, bl; unpack8(wbuf, bh, bl);
        MM3(ah, al, bh, bl, acc);
    }
    float* dst = xfp + ((size_t)(kc * 64 + b)) * 64 * 64;
    #pragma unroll
    for (int r = 0; r < 16; ++r) {
        int j = mt * 32 + (r & 3) + 8 * (r >> 2) + 4 * (l >> 5);
        dst[j * 64 + wv] = acc[r];
    }
}

__global__ __launch_bounds__(256) void xreduce_kernel(const float* __restrict__ xfp,
                                                      float* __restrict__ xfb) {
    int idx = blockIdx.x * 256 + threadIdx.x;   // 262144
    float v = 0.f;
    #pragma unroll
    for (int kc = 0; kc < KSPLIT; ++kc) v += xfp[(size_t)kc * 262144 + idx];
    xfb[idx] = v;
}

// ---------------- spectral mix: Y[(b,o)][j] bf16 hi/lo planes ----------------
__global__ __launch_bounds__(256) void specmix_kernel(const float* __restrict__ xfb,
                                                      const float* __restrict__ wr,
                                                      const float* __restrict__ wi,
                                                      ushort* __restrict__ yh,
                                                      ushort* __restrict__ yl) {
    int tid = blockIdx.x * 256 + threadIdx.x;   // 131072
    int m = tid & 31, o = (tid >> 5) & 63, b = tid >> 11;
    float yr = 0.f, yim = 0.f;
    #pragma unroll 4
    for (int i = 0; i < WW; ++i) {
        float xr = xfb[((size_t)(b * 64 + m)) * 64 + i];
        float xi = xfb[((size_t)(b * 64 + 32 + m)) * 64 + i];
        float ar = wr[((size_t)(i * 64 + o)) * 32 + m];
        float ai = wi[((size_t)(i * 64 + o)) * 32 + m];
        yr  += xr * ar - xi * ai;
        yim += xr * ai + xi * ar;
    }
    size_t base = ((size_t)b * 64 + o) * 64;
    u32 pr = packf(yr), pi = packf(yim);
    yh[base + m] = (ushort)(pr & 0xffffu);      yl[base + m] = (ushort)(pr >> 16);
    yh[base + 32 + m] = (ushort)(pi & 0xffffu); yl[base + 32 + m] = (ushort)(pi >> 16);
}

// ------------- fused iDFT + pointwise conv + bias + GELU, in-place on hc -------------
__global__ __launch_bounds__(256) void idft_pw_kernel(const ushort* __restrict__ yh,
                                                      const ushort* __restrict__ yl,
                                                      const ushort* __restrict__ ith,
                                                      const ushort* __restrict__ itl,
                                                      const ushort* __restrict__ pwh,
                                                      const ushort* __restrict__ pwl,
                                                      const float* __restrict__ pwb,
                                                      u32* __restrict__ hc) {
    const int t0 = blockIdx.x << 6, b = blockIdx.y;
    const int tid = threadIdx.x, l = tid & 63, q = tid >> 6;
    const int mt = q >> 1, nt = q & 1;
    const int lo_ = mt * 32 + (l & 31);           // o (A row / output row)
    const int lt  = t0 + nt * 32 + (l & 31);      // t (B col / output col)
    const int kh = (l >> 5) * 8;
    f32x16 acc; ACC_ZERO(acc);

    // phase 1: spec[o][t] = sum_j Y[b][o][j] * itabT[t][j]
    #pragma unroll
    for (int ks = 0; ks < 4; ++ks) {
        int k0 = ks * 16 + kh;
        bf16x8 ah = *(const bf16x8*)(yh + ((size_t)b * 64 + lo_) * 64 + k0);
        bf16x8 al = *(const bf16x8*)(yl + ((size_t)b * 64 + lo_) * 64 + k0);
        bf16x8 bh = *(const bf16x8*)(ith + (size_t)lt * 64 + k0);
        bf16x8 bl = *(const bf16x8*)(itl + (size_t)lt * 64 + k0);
        MM3(ah, al, bh, bl, acc);
    }
    // phase 2: pw[o][t] = sum_w pww[o][w] * h[b][t][w]
    #pragma unroll
    for (int ks = 0; ks < 4; ++ks) {
        int k0 = ks * 16 + kh;
        bf16x8 ah = *(const bf16x8*)(pwh + (size_t)lo_ * 64 + k0);
        bf16x8 al = *(const bf16x8*)(pwl + (size_t)lo_ * 64 + k0);
        u32 wbuf[8];
        const u32* p = hc + ((size_t)b * TT + lt) * 64 + k0;
        *(uint4*)(wbuf)     = *(const uint4*)(p);
        *(uint4*)(wbuf + 4) = *(const uint4*)(p + 4);
        bf16x8 bh, bl; unpack8(wbuf, bh, bl);
        MM3(ah, al, bh, bl, acc);
    }

    __syncthreads();   // all waves finish reading hc tile before in-place overwrite

    #pragma unroll
    for (int rq = 0; rq < 4; ++rq) {
        int ob = mt * 32 + 8 * rq + 4 * (l >> 5);
        u32 ovals[4];
        #pragma unroll
        for (int i = 0; i < 4; ++i) {
            float v = acc[rq * 4 + i] + pwb[ob + i];
            ovals[i] = packf(gelu_exact(v));
        }
        *(uint4*)(hc + ((size_t)b * TT + lt) * 64 + ob) = *(uint4*)ovals;
    }
}

// ------------- fused proj1(gelu) + proj2 -> sc[b][t] (packed) -------------
__global__ __launch_bounds__(256) void proj_kernel(const u32* __restrict__ hc,
                                                   const ushort* __restrict__ p1h,
                                                   const ushort* __restrict__ p1l,
                                                   const float* __restrict__ p1b,
                                                   const float* __restrict__ p2w,
                                                   const float* __restrict__ p2b,
                                                   u32* __restrict__ sc) {
    __shared__ float red[4][2][32];
    const int t0 = blockIdx.x << 6, b = blockIdx.y;
    const int tid = threadIdx.x, l = tid & 63, q = tid >> 6;
    const int mt = q >> 1, nt = q & 1;
    const int lw_ = mt * 32 + (l & 31);           // wp row
    const int lt  = t0 + nt * 32 + (l & 31);      // t col
    const int kh = (l >> 5) * 8;
    f32x16 acc; ACC_ZERO(acc);
    #pragma unroll
    for (int ks = 0; ks < 4; ++ks) {
        int k0 = ks * 16 + kh;
        bf16x8 ah = *(const bf16x8*)(p1h + (size_t)lw_ * 64 + k0);
        bf16x8 al = *(const bf16x8*)(p1l + (size_t)lw_ * 64 + k0);
        u32 wbuf[8];
        const u32* p = hc + ((size_t)b * TT + lt) * 64 + k0;
        *(uint4*)(wbuf)     = *(const uint4*)(p);
        *(uint4*)(wbuf + 4) = *(const uint4*)(p + 4);
        bf16x8 bh, bl; unpack8(wbuf, bh, bl);
        MM3(ah, al, bh, bl, acc);
    }
    float part = 0.f;
    #pragma unroll
    for (int r = 0; r < 16; ++r) {
        int wp = mt * 32 + (r & 3) + 8 * (r >> 2) + 4 * (l >> 5);
        part += gelu_exact(acc[r] + p1b[wp]) * p2w[wp];
    }
    red[q][l >> 5][l & 31] = part;
    __syncthreads();
    if (tid < 64) {
        int ntc = tid >> 5, c = tid & 31;
        float v = red[ntc][0][c] + red[ntc][1][c] + red[ntc + 2][0][c] + red[ntc + 2][1][c] + p2b[0];
        sc[(size_t)b * TT + t0 + tid] = packf(v);
    }
}

// ------------- token mixing: tokPart[kc][b][u] = sum_{t in chunk} s[b][t]*tokw[u][t] -------------
__global__ __launch_bounds__(256) void tok_kernel(const u32* __restrict__ sc,
                                                  const float* __restrict__ tokw,
                                                  float* __restrict__ tkp) {
    const int u0 = blockIdx.x << 6, kc = blockIdx.y;
    const int tid = threadIdx.x, l = tid & 63, q = tid >> 6;
    const int mt = q >> 1, nt = q & 1;
    const int lb_ = mt * 32 + (l & 31);           // b row
    const int lu  = u0 + nt * 32 + (l & 31);      // u col
    const int kh = (l >> 5) * 8;
    f32x16 acc; ACC_ZERO(acc);
    for (int ks = 0; ks < 32; ++ks) {
        int k0 = kc * 512 + ks * 16 + kh;
        u32 wbuf[8];
        const u32* p = sc + (size_t)lb_ * TT + k0;
        *(uint4*)(wbuf)     = *(const uint4*)(p);
        *(uint4*)(wbuf + 4) = *(const uint4*)(p + 4);
        bf16x8 ah, al; unpack8(wbuf, ah, al);
        float fbuf[8];
        const float* tp = tokw + (size_t)lu * TT + k0;
        *(float4*)(fbuf)     = *(const float4*)(tp);
        *(float4*)(fbuf + 4) = *(const float4*)(tp + 4);
        bf16x8 bh, bl; cvt8(fbuf, bh, bl);
        MM3(ah, al, bh, bl, acc);
    }
    #pragma unroll
    for (int r = 0; r < 16; ++r) {
        int br = mt * 32 + (r & 3) + 8 * (r >> 2) + 4 * (l >> 5);
        tkp[((size_t)(kc * 64 + br)) * OUTT + lu] = acc[r];
    }
}

__global__ __launch_bounds__(256) void tok_reduce_kernel(const float* __restrict__ tkp,
                                                         const float* __restrict__ tokb,
                                                         float* __restrict__ out) {
    int idx = blockIdx.x * 256 + threadIdx.x;   // 262144
    int u = idx & (OUTT - 1);
    float v = tokb[u];
    #pragma unroll
    for (int kc = 0; kc < KSPLIT; ++kc) v += tkp[(size_t)kc * 262144 + idx];
    out[idx] = v;
}

extern "C" void kernel_launch(void* const* d_in, const int* in_sizes, int n_in,
                              void* d_out, int out_size, void* d_ws, size_t ws_size,
                              hipStream_t stream) {
    const float* x    = (const float*)d_in[0];
    const float* lw   = (const float*)d_in[1];
    const float* lb   = (const float*)d_in[2];
    const float* swr  = (const float*)d_in[3];
    const float* swi  = (const float*)d_in[4];
    const float* pww  = (const float*)d_in[5];
    const float* pwb  = (const float*)d_in[6];
    const float* p1w  = (const float*)d_in[7];
    const float* p1b  = (const float*)d_in[8];
    const float* p2w  = (const float*)d_in[9];
    const float* p2b  = (const float*)d_in[10];
    const float* tokw = (const float*)d_in[11];
    const float* tokb = (const float*)d_in[12];
    float* out = (float*)d_out;

    float* ws = (float*)d_ws;
    u32*    hc  = (u32*)(ws + OFF_HC);
    ushort* fth = (ushort*)(ws + OFF_FTH);
    ushort* ftl = (ushort*)(ws + OFF_FTL);
    ushort* ith = (ushort*)(ws + OFF_ITH);
    ushort* itl = (ushort*)(ws + OFF_ITL);
    ushort* pwh = (ushort*)(ws + OFF_PWH);
    ushort* pwl = (ushort*)(ws + OFF_PWL);
    ushort* p1h = (ushort*)(ws + OFF_P1H);
    ushort* p1l = (ushort*)(ws + OFF_P1L);
    ushort* yh  = (ushort*)(ws + OFF_YH);
    ushort* yl  = (ushort*)(ws + OFF_YL);
    float*  xfp = ws + OFF_XFP;          // shared: xfPart / tokPart
    float*  xfb = ws + OFF_XFB;
    u32*    sc  = (u32*)(ws + OFF_SC);

    build_tables_kernel<<<(64 * TT) / 256, 256, 0, stream>>>(fth, ftl, ith, itl);
    wconv_kernel<<<80, 256, 0, stream>>>(pww, p1w, pwh, pwl, p1h, p1l);
    lift_kernel<<<(BB * WW * TT) / 256, 256, 0, stream>>>(x, lw, lb, hc);

    for (int l = 0; l < NLAYER; ++l) {
        dft_kernel<<<dim3(BB, KSPLIT), 256, 0, stream>>>(hc, fth, ftl, xfp);
        xreduce_kernel<<<1024, 256, 0, stream>>>(xfp, xfb);
        specmix_kernel<<<512, 256, 0, stream>>>(
            xfb, swr + (size_t)l * WW * WW * MODES, swi + (size_t)l * WW * WW * MODES, yh, yl);
        idft_pw_kernel<<<dim3(TT / 64, BB), 256, 0, stream>>>(
            yh, yl, ith, itl, pwh + (size_t)l * WW * WW, pwl + (size_t)l * WW * WW,
            pwb + (size_t)l * WW, hc);
    }

    proj_kernel<<<dim3(TT / 64, BB), 256, 0, stream>>>(hc, p1h, p1l, p1b, p2w, p2b, sc);
    tok_kernel<<<dim3(OUTT / 64, KSPLIT), 256, 0, stream>>>(sc, tokw, xfp);
    tok_reduce_kernel<<<1024, 256, 0, stream>>>(xfp, tokb, out);
}

// Round 4
// 348.863 us; speedup vs baseline: 57.6893x; 1.6039x over previous
//
#include <hip/hip_runtime.h>
#include <math.h>
#include <stdint.h>

#define BB 64
#define TT 4096
#define WW 64
#define MODES 32
#define NLAYER 4
#define OUTT 4096
#define KSPLIT 8

typedef uint32_t u32;
typedef __attribute__((ext_vector_type(8))) short bf16x8;
typedef __attribute__((ext_vector_type(16))) float f32x16;

// ws layout (float offsets)
#define OFF_HC   0            // hc[b][t][w] packed bf16 hi|lo u32, 16,777,216
#define OFF_FTH  16777216     // ftabT_hi [64 j][4096 t] ushort
#define OFF_FTL  16908288
#define OFF_ITH  17039360     // itabT_hi [4096 t][64 j] ushort
#define OFF_ITL  17170432
#define OFF_PWH  17301504     // pww planes [4][64][64] ushort
#define OFF_PWL  17309696
#define OFF_P1H  17317888     // p1w planes [64][64] ushort
#define OFF_P1L  17319936
#define OFF_YH   17321984     // Y_hi [4096 (b,o)][64 j] ushort
#define OFF_YL   17453056
#define OFF_XFP  17584128     // xfPart [8][64][64][64] f32 / tok partials [8][64][4096]
#define OFF_XFB  19681280     // xfb [64][64][64] f32 ; also xfxT scratch早期
#define OFF_SC   19943424     // sc [64][4096] packed u32
#define OFF_PWLW 20205568     // [64]
#define OFF_PWLB 20205632     // [64]
#define OFF_XFXP 20205696     // [8][64][64] f32 (32768)
#define OFF_XFXT 20238464     // [64][64] f32

__device__ __forceinline__ float gelu_exact(float x) {
    return 0.5f * x * (1.0f + erff(x * 0.70710678118654752f));
}
__device__ __forceinline__ u32 bfrn(float f) {
    u32 u = __float_as_uint(f);
    return (u + 0x7fffu + ((u >> 16) & 1u)) >> 16;
}
__device__ __forceinline__ u32 packf(float f) {
    u32 h = bfrn(f);
    float r = f - __uint_as_float(h << 16);
    u32 l = bfrn(r);
    return h | (l << 16);
}
__device__ __forceinline__ void unpack8(const u32* w, bf16x8& hi, bf16x8& lo) {
    union { bf16x8 v; ushort u[8]; } H, L;
    #pragma unroll
    for (int i = 0; i < 8; ++i) { H.u[i] = (ushort)(w[i] & 0xffffu); L.u[i] = (ushort)(w[i] >> 16); }
    hi = H.v; lo = L.v;
}
__device__ __forceinline__ void cvt8(const float* f, bf16x8& hi, bf16x8& lo) {
    union { bf16x8 v; ushort u[8]; } H, L;
    #pragma unroll
    for (int i = 0; i < 8; ++i) {
        u32 h = bfrn(f[i]);
        H.u[i] = (ushort)h;
        L.u[i] = (ushort)bfrn(f[i] - __uint_as_float(h << 16));
    }
    hi = H.v; lo = L.v;
}

#define MM3(ah, al, bh, bl, acc)                                          \
    acc = __builtin_amdgcn_mfma_f32_32x32x16_bf16(ah, bh, acc, 0, 0, 0);  \
    acc = __builtin_amdgcn_mfma_f32_32x32x16_bf16(ah, bl, acc, 0, 0, 0);  \
    acc = __builtin_amdgcn_mfma_f32_32x32x16_bf16(al, bh, acc, 0, 0, 0);

#define ACC_ZERO(acc) { _Pragma("unroll") for (int _i = 0; _i < 16; ++_i) acc[_i] = 0.0f; }

// ---------------- tables ----------------
__global__ __launch_bounds__(256) void build_tables_kernel(ushort* __restrict__ fth, ushort* __restrict__ ftl,
                                                           ushort* __restrict__ ith, ushort* __restrict__ itl) {
    const int idx = blockIdx.x * 256 + threadIdx.x;
    const float w0 = 6.28318530717958647692f / (float)TT;
    {   // ftabT [j][t]
        int j = idx >> 12, t = idx & (TT - 1), m = j & 31;
        float ang = (float)((m * t) & (TT - 1)) * w0;
        float s, c; sincosf(ang, &s, &c);
        u32 p = packf((j < 32) ? c : -s);
        fth[idx] = (ushort)(p & 0xffffu); ftl[idx] = (ushort)(p >> 16);
    }
    {   // itabT [t][j]
        int t = idx >> 6, j = idx & 63, m = j & 31;
        float ang = (float)((m * t) & (TT - 1)) * w0;
        float s, c; sincosf(ang, &s, &c);
        float v;
        if (j == 0)       v = 1.0f / (float)TT;
        else if (j < 32)  v = (2.0f / (float)TT) * c;
        else if (j == 32) v = 0.0f;
        else              v = -(2.0f / (float)TT) * s;
        u32 p = packf(v);
        ith[idx] = (ushort)(p & 0xffffu); itl[idx] = (ushort)(p >> 16);
    }
}

// ---------------- weights: planes + layer-0 rank-1 folds ----------------
__global__ __launch_bounds__(256) void wconv_kernel(const float* __restrict__ pww, const float* __restrict__ p1w,
                                                    const float* __restrict__ lw, const float* __restrict__ lb,
                                                    const float* __restrict__ pwb,
                                                    ushort* __restrict__ pwh, ushort* __restrict__ pwl,
                                                    ushort* __restrict__ p1h, ushort* __restrict__ p1l,
                                                    float* __restrict__ pwlw, float* __restrict__ pwlb) {
    int idx = blockIdx.x * 256 + threadIdx.x;
    if (idx < NLAYER * 64 * 64) {
        u32 p = packf(pww[idx]);
        pwh[idx] = (ushort)(p & 0xffffu); pwl[idx] = (ushort)(p >> 16);
    } else if (idx < NLAYER * 64 * 64 + 64 * 64) {
        int k = idx - NLAYER * 64 * 64;
        u32 p = packf(p1w[k]);
        p1h[k] = (ushort)(p & 0xffffu); p1l[k] = (ushort)(p >> 16);
    } else if (idx < NLAYER * 64 * 64 + 64 * 64 + 64) {
        int o = idx - (NLAYER * 64 * 64 + 64 * 64);
        float aw = 0.f, ab = 0.f;
        for (int w = 0; w < 64; ++w) {
            float pv = pww[o * 64 + w];   // layer 0
            aw += pv * lw[w];
            ab += pv * lb[w];
        }
        pwlw[o] = aw;
        pwlb[o] = ab + pwb[o];           // fold layer-0 pw bias
    }
}

// ---------------- dftx: xfxp[kc][j][b] = sum_{t in chunk} ftabT[j][t] x[b][t] ----------------
__global__ __launch_bounds__(256) void dftx_kernel(const float* __restrict__ x,
                                                   const ushort* __restrict__ fth,
                                                   const ushort* __restrict__ ftl,
                                                   float* __restrict__ xfxp) {
    const int kc = blockIdx.x;
    const int tid = threadIdx.x, l = tid & 63, q = tid >> 6;
    const int mt = q >> 1, nt = q & 1;
    const int lr = mt * 32 + (l & 31);       // j
    const int bc = nt * 32 + (l & 31);       // b
    const int kh = (l >> 5) * 8;
    f32x16 acc; ACC_ZERO(acc);
    for (int ks = 0; ks < 32; ++ks) {
        int k0 = kc * 512 + ks * 16 + kh;
        bf16x8 ah = *(const bf16x8*)(fth + (size_t)lr * TT + k0);
        bf16x8 al = *(const bf16x8*)(ftl + (size_t)lr * TT + k0);
        float fbuf[8];
        *(float4*)(fbuf)     = *(const float4*)(x + (size_t)bc * TT + k0);
        *(float4*)(fbuf + 4) = *(const float4*)(x + (size_t)bc * TT + k0 + 4);
        bf16x8 bh, bl; cvt8(fbuf, bh, bl);
        MM3(ah, al, bh, bl, acc);
    }
    #pragma unroll
    for (int r = 0; r < 16; ++r) {
        int j = mt * 32 + (r & 3) + 8 * (r >> 2) + 4 * (l >> 5);
        xfxp[(size_t)kc * 4096 + j * 64 + bc] = acc[r];
    }
}

__global__ __launch_bounds__(256) void xfx_reduce_kernel(const float* __restrict__ xfxp,
                                                         float* __restrict__ xfxT) {
    int idx = blockIdx.x * 256 + threadIdx.x;   // 4096
    float v = 0.f;
    #pragma unroll
    for (int kc = 0; kc < KSPLIT; ++kc) v += xfxp[(size_t)kc * 4096 + idx];
    xfxT[idx] = v;
}

// ---------------- specmix layer-0 (analytic xf from rank-1 lift) ----------------
__global__ __launch_bounds__(256) void specmix0_kernel(const float* __restrict__ xfxT,
                                                       const float* __restrict__ lw,
                                                       const float* __restrict__ lb,
                                                       const float* __restrict__ wr,
                                                       const float* __restrict__ wi,
                                                       ushort* __restrict__ yh,
                                                       ushort* __restrict__ yl) {
    int tid = blockIdx.x * 256 + threadIdx.x;
    int m = tid & 31, o = (tid >> 5) & 63, b = tid >> 11;
    float xvr = xfxT[m * 64 + b];
    float xvi = xfxT[(32 + m) * 64 + b];
    float c0 = (m == 0) ? (float)TT : 0.0f;
    float yr = 0.f, yim = 0.f;
    #pragma unroll 4
    for (int i = 0; i < WW; ++i) {
        float xr = lw[i] * xvr + c0 * lb[i];
        float xi = lw[i] * xvi;
        float ar = wr[((size_t)(i * 64 + o)) * 32 + m];
        float ai = wi[((size_t)(i * 64 + o)) * 32 + m];
        yr  += xr * ar - xi * ai;
        yim += xr * ai + xi * ar;
    }
    size_t base = ((size_t)b * 64 + o) * 64;
    u32 pr = packf(yr), pi = packf(yim);
    yh[base + m] = (ushort)(pr & 0xffffu);      yl[base + m] = (ushort)(pr >> 16);
    yh[base + 32 + m] = (ushort)(pi & 0xffffu); yl[base + 32 + m] = (ushort)(pi >> 16);
}

// ---------------- specmix (standard, from xfb) ----------------
__global__ __launch_bounds__(256) void specmix_kernel(const float* __restrict__ xfb,
                                                      const float* __restrict__ wr,
                                                      const float* __restrict__ wi,
                                                      ushort* __restrict__ yh,
                                                      ushort* __restrict__ yl) {
    int tid = blockIdx.x * 256 + threadIdx.x;
    int m = tid & 31, o = (tid >> 5) & 63, b = tid >> 11;
    float yr = 0.f, yim = 0.f;
    #pragma unroll 4
    for (int i = 0; i < WW; ++i) {
        float xr = xfb[((size_t)(b * 64 + m)) * 64 + i];
        float xi = xfb[((size_t)(b * 64 + 32 + m)) * 64 + i];
        float ar = wr[((size_t)(i * 64 + o)) * 32 + m];
        float ai = wi[((size_t)(i * 64 + o)) * 32 + m];
        yr  += xr * ar - xi * ai;
        yim += xr * ai + xi * ar;
    }
    size_t base = ((size_t)b * 64 + o) * 64;
    u32 pr = packf(yr), pi = packf(yim);
    yh[base + m] = (ushort)(pr & 0xffffu);      yl[base + m] = (ushort)(pr >> 16);
    yh[base + 32 + m] = (ushort)(pi & 0xffffu); yl[base + 32 + m] = (ushort)(pi >> 16);
}

__global__ __launch_bounds__(256) void xreduce_kernel(const float* __restrict__ xfp,
                                                      float* __restrict__ xfb) {
    int idx = blockIdx.x * 256 + threadIdx.x;   // 262144
    float v = 0.f;
    #pragma unroll
    for (int kc = 0; kc < KSPLIT; ++kc) v += xfp[(size_t)kc * 262144 + idx];
    xfb[idx] = v;
}

// ============ fused layer: spec + pw + GELU -> hc, and accumulate next DFT partial ============
// grid (kc=8, b=64), 256 thr. Each block: 8 t-tiles of 64.
template<int IS_L0>
__global__ __launch_bounds__(256) void layer_kernel(u32* __restrict__ hc,
                                                    const ushort* __restrict__ yh, const ushort* __restrict__ yl,
                                                    const ushort* __restrict__ ith, const ushort* __restrict__ itl,
                                                    const ushort* __restrict__ pwh, const ushort* __restrict__ pwl,
                                                    const float* __restrict__ pwb,
                                                    const float* __restrict__ x,
                                                    const float* __restrict__ pwlw, const float* __restrict__ pwlb,
                                                    const ushort* __restrict__ fth, const ushort* __restrict__ ftl,
                                                    float* __restrict__ xfp) {
    __shared__ u32 lpw[64 * 64];     // pw input tile, XOR-16B-slot swizzle
    __shared__ u32 lht[64 * 68];     // new h tile, [o][t] pad-68
    const int kc = blockIdx.x, b = blockIdx.y;
    const int tid = threadIdx.x, l = tid & 63, q = tid >> 6;
    const int mt = q >> 1, nt = q & 1;
    const int lr  = mt * 32 + (l & 31);      // A-row (o or j)
    const int ltc = nt * 32 + (l & 31);      // tile-local col t / B-col w
    const int kh = (l >> 5) * 8;
    f32x16 aF; ACC_ZERO(aF);                 // DFT partial accumulator

    // hoist tile-invariant A-fragments (Y and pw planes)
    bf16x8 ya[4], yb[4], pa[4], pb[4];
    #pragma unroll
    for (int ks = 0; ks < 4; ++ks) {
        int k0 = ks * 16 + kh;
        ya[ks] = *(const bf16x8*)(yh + ((size_t)b * 64 + lr) * 64 + k0);
        yb[ks] = *(const bf16x8*)(yl + ((size_t)b * 64 + lr) * 64 + k0);
        if (!IS_L0) {
            pa[ks] = *(const bf16x8*)(pwh + (size_t)lr * 64 + k0);
            pb[ks] = *(const bf16x8*)(pwl + (size_t)lr * 64 + k0);
        }
    }

    for (int tile = 0; tile < 8; ++tile) {
        const int tbase = kc * 512 + tile * 64;
        f32x16 acc; ACC_ZERO(acc);
        __syncthreads();
        if (!IS_L0) {
            #pragma unroll
            for (int i = 0; i < 4; ++i) {
                int e = tid + (i << 8);
                int t = e >> 4, sl = e & 15;
                uint4 v = *(const uint4*)(hc + (((size_t)b * TT + tbase + t) << 6) + (sl << 2));
                *(uint4*)&lpw[(t << 6) + ((sl ^ (t & 15)) << 2)] = v;
            }
        }
        __syncthreads();
        // spec GEMM: A=Y[b], B=itabT
        #pragma unroll
        for (int ks = 0; ks < 4; ++ks) {
            int k0 = ks * 16 + kh;
            bf16x8 bh = *(const bf16x8*)(ith + (size_t)(tbase + ltc) * 64 + k0);
            bf16x8 bl = *(const bf16x8*)(itl + (size_t)(tbase + ltc) * 64 + k0);
            MM3(ya[ks], yb[ks], bh, bl, acc);
        }
        float xv = 0.f;
        if (!IS_L0) {
            // pw GEMM: A=pww, B=h_in from LDS
            #pragma unroll
            for (int ks = 0; ks < 4; ++ks) {
                int k0 = ks * 16 + kh;
                int s0 = k0 >> 2;
                u32 wbuf[8];
                *(uint4*)(wbuf)     = *(const uint4*)&lpw[(ltc << 6) + ((s0       ^ (ltc & 15)) << 2)];
                *(uint4*)(wbuf + 4) = *(const uint4*)&lpw[(ltc << 6) + (((s0 + 1) ^ (ltc & 15)) << 2)];
                bf16x8 bh, bl; unpack8(wbuf, bh, bl);
                MM3(pa[ks], pb[ks], bh, bl, acc);
            }
        } else {
            xv = x[(size_t)b * TT + tbase + ltc];
        }
        // epilogue: bias (+rank-1 pw for L0), gelu, pack; write hc + lht
        #pragma unroll
        for (int rq = 0; rq < 4; ++rq) {
            int ob = mt * 32 + 8 * rq + 4 * (l >> 5);
            u32 ov[4];
            #pragma unroll
            for (int i = 0; i < 4; ++i) {
                float v = acc[rq * 4 + i];
                if (IS_L0) v += pwlw[ob + i] * xv + pwlb[ob + i];
                else       v += pwb[ob + i];
                ov[i] = packf(gelu_exact(v));
            }
            *(uint4*)(hc + (((size_t)b * TT + tbase + ltc) << 6) + ob) = *(uint4*)ov;
            #pragma unroll
            for (int i = 0; i < 4; ++i) lht[(ob + i) * 68 + ltc] = ov[i];
        }
        __syncthreads();
        // DFT accumulate: A=ftabT slice, B=lht[w][t']
        #pragma unroll
        for (int ks = 0; ks < 4; ++ks) {
            int k0 = ks * 16 + kh;
            bf16x8 ah = *(const bf16x8*)(fth + (size_t)lr * TT + tbase + k0);
            bf16x8 al = *(const bf16x8*)(ftl + (size_t)lr * TT + tbase + k0);
            u32 wbuf[8];
            *(uint4*)(wbuf)     = *(const uint4*)&lht[ltc * 68 + k0];
            *(uint4*)(wbuf + 4) = *(const uint4*)&lht[ltc * 68 + k0 + 4];
            bf16x8 bh, bl; unpack8(wbuf, bh, bl);
            MM3(ah, al, bh, bl, aF);
        }
    }
    float* dst = xfp + ((size_t)(kc * 64 + b)) * 4096;
    #pragma unroll
    for (int r = 0; r < 16; ++r) {
        int j = mt * 32 + (r & 3) + 8 * (r >> 2) + 4 * (l >> 5);
        dst[j * 64 + ltc] = aF[r];
    }
}

// ============ last layer: spec + pw + GELU + proj1(gelu) + proj2 -> sc ============
__global__ __launch_bounds__(256) void layer3_kernel(const u32* __restrict__ hc,
                                                     const ushort* __restrict__ yh, const ushort* __restrict__ yl,
                                                     const ushort* __restrict__ ith, const ushort* __restrict__ itl,
                                                     const ushort* __restrict__ pwh, const ushort* __restrict__ pwl,
                                                     const float* __restrict__ pwb,
                                                     const ushort* __restrict__ p1h, const ushort* __restrict__ p1l,
                                                     const float* __restrict__ p1b,
                                                     const float* __restrict__ p2w, const float* __restrict__ p2b,
                                                     u32* __restrict__ sc) {
    __shared__ u32 lpw[64 * 64];
    __shared__ u32 lht[64 * 68];
    __shared__ float red[4][64];
    const int t0 = blockIdx.x << 6, b = blockIdx.y;
    const int tid = threadIdx.x, l = tid & 63, q = tid >> 6;
    const int mt = q >> 1, nt = q & 1;
    const int lr  = mt * 32 + (l & 31);
    const int ltc = nt * 32 + (l & 31);
    const int kh = (l >> 5) * 8;
    f32x16 acc; ACC_ZERO(acc);

    #pragma unroll
    for (int i = 0; i < 4; ++i) {
        int e = tid + (i << 8);
        int t = e >> 4, sl = e & 15;
        uint4 v = *(const uint4*)(hc + (((size_t)b * TT + t0 + t) << 6) + (sl << 2));
        *(uint4*)&lpw[(t << 6) + ((sl ^ (t & 15)) << 2)] = v;
    }
    __syncthreads();
    #pragma unroll
    for (int ks = 0; ks < 4; ++ks) {
        int k0 = ks * 16 + kh;
        bf16x8 ah = *(const bf16x8*)(yh + ((size_t)b * 64 + lr) * 64 + k0);
        bf16x8 al = *(const bf16x8*)(yl + ((size_t)b * 64 + lr) * 64 + k0);
        bf16x8 bh = *(const bf16x8*)(ith + (size_t)(t0 + ltc) * 64 + k0);
        bf16x8 bl = *(const bf16x8*)(itl + (size_t)(t0 + ltc) * 64 + k0);
        MM3(ah, al, bh, bl, acc);
    }
    #pragma unroll
    for (int ks = 0; ks < 4; ++ks) {
        int k0 = ks * 16 + kh;
        int s0 = k0 >> 2;
        bf16x8 ah = *(const bf16x8*)(pwh + (size_t)lr * 64 + k0);
        bf16x8 al = *(const bf16x8*)(pwl + (size_t)lr * 64 + k0);
        u32 wbuf[8];
        *(uint4*)(wbuf)     = *(const uint4*)&lpw[(ltc << 6) + ((s0       ^ (ltc & 15)) << 2)];
        *(uint4*)(wbuf + 4) = *(const uint4*)&lpw[(ltc << 6) + (((s0 + 1) ^ (ltc & 15)) << 2)];
        bf16x8 bh, bl; unpack8(wbuf, bh, bl);
        MM3(ah, al, bh, bl, acc);
    }
    // h3 tile -> lht only (never to HBM)
    #pragma unroll
    for (int rq = 0; rq < 4; ++rq) {
        int ob = mt * 32 + 8 * rq + 4 * (l >> 5);
        #pragma unroll
        for (int i = 0; i < 4; ++i) {
            float v = acc[rq * 4 + i] + pwb[ob + i];
            lht[(ob + i) * 68 + ltc] = packf(gelu_exact(v));
        }
    }
    __syncthreads();
    // proj1 GEMM: A=p1w planes [wp][w], B=lht[w][t] (column reads, conflict-free)
    f32x16 a2; ACC_ZERO(a2);
    #pragma unroll
    for (int ks = 0; ks < 4; ++ks) {
        int k0 = ks * 16 + kh;
        bf16x8 ah = *(const bf16x8*)(p1h + (size_t)lr * 64 + k0);
        bf16x8 al = *(const bf16x8*)(p1l + (size_t)lr * 64 + k0);
        u32 wbuf[8];
        #pragma unroll
        for (int i = 0; i < 8; ++i) wbuf[i] = lht[(k0 + i) * 68 + ltc];
        bf16x8 bh, bl; unpack8(wbuf, bh, bl);
        MM3(ah, al, bh, bl, a2);
    }
    float part = 0.f;
    #pragma unroll
    for (int r = 0; r < 16; ++r) {
        int wp = mt * 32 + (r & 3) + 8 * (r >> 2) + 4 * (l >> 5);
        part += gelu_exact(a2[r] + p1b[wp]) * p2w[wp];
    }
    red[q][l] = part;
    __syncthreads();
    if (tid < 64) {
        int hn = tid >> 5, c = tid & 31;
        float v = red[hn][c] + red[hn][c + 32] + red[2 + hn][c] + red[2 + hn][c + 32] + p2b[0];
        sc[(size_t)b * TT + t0 + tid] = packf(v);
    }
}

// ------------- token mixing partials + reduce (unchanged) -------------
__global__ __launch_bounds__(256) void tok_kernel(const u32* __restrict__ sc,
                                                  const float* __restrict__ tokw,
                                                  float* __restrict__ tkp) {
    const int u0 = blockIdx.x << 6, kc = blockIdx.y;
    const int tid = threadIdx.x, l = tid & 63, q = tid >> 6;
    const int mt = q >> 1, nt = q & 1;
    const int lb_ = mt * 32 + (l & 31);
    const int lu  = u0 + nt * 32 + (l & 31);
    const int kh = (l >> 5) * 8;
    f32x16 acc; ACC_ZERO(acc);
    for (int ks = 0; ks < 32; ++ks) {
        int k0 = kc * 512 + ks * 16 + kh;
        u32 wbuf[8];
        const u32* p = sc + (size_t)lb_ * TT + k0;
        *(uint4*)(wbuf)     = *(const uint4*)(p);
        *(uint4*)(wbuf + 4) = *(const uint4*)(p + 4);
        bf16x8 ah, al; unpack8(wbuf, ah, al);
        float fbuf[8];
        const float* tp = tokw + (size_t)lu * TT + k0;
        *(float4*)(fbuf)     = *(const float4*)(tp);
        *(float4*)(fbuf + 4) = *(const float4*)(tp + 4);
        bf16x8 bh, bl; cvt8(fbuf, bh, bl);
        MM3(ah, al, bh, bl, acc);
    }
    #pragma unroll
    for (int r = 0; r < 16; ++r) {
        int br = mt * 32 + (r & 3) + 8 * (r >> 2) + 4 * (l >> 5);
        tkp[((size_t)(kc * 64 + br)) * OUTT + lu] = acc[r];
    }
}

__global__ __launch_bounds__(256) void tok_reduce_kernel(const float* __restrict__ tkp,
                                                         const float* __restrict__ tokb,
                                                         float* __restrict__ out) {
    int idx = blockIdx.x * 256 + threadIdx.x;
    int u = idx & (OUTT - 1);
    float v = tokb[u];
    #pragma unroll
    for (int kc = 0; kc < KSPLIT; ++kc) v += tkp[(size_t)kc * 262144 + idx];
    out[idx] = v;
}

extern "C" void kernel_launch(void* const* d_in, const int* in_sizes, int n_in,
                              void* d_out, int out_size, void* d_ws, size_t ws_size,
                              hipStream_t stream) {
    const float* x    = (const float*)d_in[0];
    const float* lw   = (const float*)d_in[1];
    const float* lb   = (const float*)d_in[2];
    const float* swr  = (const float*)d_in[3];
    const float* swi  = (const float*)d_in[4];
    const float* pww  = (const float*)d_in[5];
    const float* pwb  = (const float*)d_in[6];
    const float* p1w  = (const float*)d_in[7];
    const float* p1b  = (const float*)d_in[8];
    const float* p2w  = (const float*)d_in[9];
    const float* p2b  = (const float*)d_in[10];
    const float* tokw = (const float*)d_in[11];
    const float* tokb = (const float*)d_in[12];
    float* out = (float*)d_out;

    float* ws = (float*)d_ws;
    u32*    hc   = (u32*)(ws + OFF_HC);
    ushort* fth  = (ushort*)(ws + OFF_FTH);
    ushort* ftl  = (ushort*)(ws + OFF_FTL);
    ushort* ith  = (ushort*)(ws + OFF_ITH);
    ushort* itl  = (ushort*)(ws + OFF_ITL);
    ushort* pwh  = (ushort*)(ws + OFF_PWH);
    ushort* pwl  = (ushort*)(ws + OFF_PWL);
    ushort* p1h  = (ushort*)(ws + OFF_P1H);
    ushort* p1l  = (ushort*)(ws + OFF_P1L);
    ushort* yh   = (ushort*)(ws + OFF_YH);
    ushort* yl   = (ushort*)(ws + OFF_YL);
    float*  xfp  = ws + OFF_XFP;
    float*  xfb  = ws + OFF_XFB;
    u32*    sc   = (u32*)(ws + OFF_SC);
    float*  pwlw = ws + OFF_PWLW;
    float*  pwlb = ws + OFF_PWLB;
    float*  xfxp = ws + OFF_XFXP;
    float*  xfxT = ws + OFF_XFXT;

    build_tables_kernel<<<1024, 256, 0, stream>>>(fth, ftl, ith, itl);
    wconv_kernel<<<81, 256, 0, stream>>>(pww, p1w, lw, lb, pwb, pwh, pwl, p1h, p1l, pwlw, pwlb);

    // layer 0 input spectrum from rank-1 lift
    dftx_kernel<<<8, 256, 0, stream>>>(x, fth, ftl, xfxp);
    xfx_reduce_kernel<<<16, 256, 0, stream>>>(xfxp, xfxT);
    specmix0_kernel<<<512, 256, 0, stream>>>(xfxT, lw, lb, swr, swi, yh, yl);

    // layer 0 (no hc read) — also produces layer-1 DFT partials
    layer_kernel<1><<<dim3(KSPLIT, BB), 256, 0, stream>>>(
        hc, yh, yl, ith, itl, pwh, pwl, pwb, x, pwlw, pwlb, fth, ftl, xfp);

    for (int l = 1; l < NLAYER; ++l) {
        xreduce_kernel<<<1024, 256, 0, stream>>>(xfp, xfb);
        specmix_kernel<<<512, 256, 0, stream>>>(
            xfb, swr + (size_t)l * WW * WW * MODES, swi + (size_t)l * WW * WW * MODES, yh, yl);
        if (l < NLAYER - 1) {
            layer_kernel<0><<<dim3(KSPLIT, BB), 256, 0, stream>>>(
                hc, yh, yl, ith, itl, pwh + (size_t)l * 4096, pwl + (size_t)l * 4096,
                pwb + (size_t)l * 64, x, pwlw, pwlb, fth, ftl, xfp);
        } else {
            layer3_kernel<<<dim3(TT / 64, BB), 256, 0, stream>>>(
                hc, yh, yl, ith, itl, pwh + (size_t)l * 4096, pwl + (size_t)l * 4096,
                pwb + (size_t)l * 64, p1h, p1l, p1b, p2w, p2b, sc);
        }
    }

    tok_kernel<<<dim3(OUTT / 64, KSPLIT), 256, 0, stream>>>(sc, tokw, xfp);
    tok_reduce_kernel<<<1024, 256, 0, stream>>>(xfp, tokb, out);
}